// Round 5
// baseline (424.942 us; speedup 1.0000x reference)
//
#include <hip/hip_runtime.h>
#include <hip/hip_bf16.h>

#define IN_F 8192
#define OUT_F 8192
#define STATE_THRESHOLD 50.0f

typedef float f32x4 __attribute__((ext_vector_type(4)));
typedef unsigned int u32x4 __attribute__((ext_vector_type(4)));

// MEASUREMENT ROUND: R4 kernel + a second 256 MiB streaming read from d_ws.
// The ws values are folded into the integer accumulator via an always-false
// compare (ws is poisoned 0xAA bytes), so output is unchanged but the loads
// cannot be elided. dur_us delta vs R4 = 256 MiB / achieved_read_BW.
__global__ __launch_bounds__(512, 8) void snn_gemv_probe_kernel(
    const float* __restrict__ spike_input,      // [IN_F]
    const float* __restrict__ synapse_states,   // [OUT_F, IN_F]
    const float* __restrict__ membrane,         // [OUT_F]
    const float* __restrict__ adaptive_thresh,  // [OUT_F]
    const float* __restrict__ noise,            // [OUT_F]
    const u32x4* __restrict__ ws,               // scratch, poisoned 0xAA
    unsigned int wsChunks,                      // # of 32 KiB chunks in ws
    float* __restrict__ out)                    // [OUT_F]
{
    const int tid  = threadIdx.x;
    const int lane = tid & 63;
    const int wave = tid >> 6;

    // Pack this lane's 128 gate bits into two u64 (register-resident).
    const f32x4* sp4 = (const f32x4*)spike_input;
    unsigned long long b0 = 0ull, b1 = 0ull;
#pragma unroll
    for (int i = 0; i < 16; ++i) {
        f32x4 x = sp4[lane + 64 * i];
        unsigned long long nib =
            (unsigned long long)((x.x > 0.5f) | ((x.y > 0.5f) << 1) |
                                 ((x.z > 0.5f) << 2) | ((x.w > 0.5f) << 3));
        b0 |= nib << (4 * i);
    }
#pragma unroll
    for (int i = 0; i < 16; ++i) {
        f32x4 x = sp4[lane + 64 * (i + 16)];
        unsigned long long nib =
            (unsigned long long)((x.x > 0.5f) | ((x.y > 0.5f) << 1) |
                                 ((x.z > 0.5f) << 2) | ((x.w > 0.5f) << 3));
        b1 |= nib << (4 * i);
    }

    const int row = blockIdx.x * 8 + wave;
    const f32x4* rowp = (const f32x4*)(synapse_states + (size_t)row * IN_F);
    // This wave's 32 KiB ws chunk (2048 uint4), wrapped to ws capacity.
    const u32x4* wsp = ws + (size_t)(row % wsChunks) * 2048;

    unsigned int cnt = 0;
#pragma unroll 4
    for (int i = 0; i < 16; ++i) {
        f32x4 s = __builtin_nontemporal_load(rowp + lane + 64 * i);
        u32x4 w = __builtin_nontemporal_load(wsp + lane + 64 * i);
        unsigned int nib = (unsigned int)(b0 >> (4 * i)) & 0xFu;
        cnt += (s.x > STATE_THRESHOLD) ? (nib & 1u) : 0u;
        cnt += (s.y > STATE_THRESHOLD) ? ((nib >> 1) & 1u) : 0u;
        cnt += (s.z > STATE_THRESHOLD) ? ((nib >> 2) & 1u) : 0u;
        cnt += (s.w > STATE_THRESHOLD) ? ((nib >> 3) & 1u) : 0u;
        // Always-false at runtime (ws is 0xAAAAAAAA poison); keeps loads live.
        cnt += (w.x == 0x13572468u) ? 1u : 0u;
        cnt += (w.w == 0x24681357u) ? 1u : 0u;
    }
#pragma unroll 4
    for (int i = 0; i < 16; ++i) {
        f32x4 s = __builtin_nontemporal_load(rowp + lane + 64 * (i + 16));
        u32x4 w = __builtin_nontemporal_load(wsp + lane + 64 * (i + 16));
        unsigned int nib = (unsigned int)(b1 >> (4 * i)) & 0xFu;
        cnt += (s.x > STATE_THRESHOLD) ? (nib & 1u) : 0u;
        cnt += (s.y > STATE_THRESHOLD) ? ((nib >> 1) & 1u) : 0u;
        cnt += (s.z > STATE_THRESHOLD) ? ((nib >> 2) & 1u) : 0u;
        cnt += (s.w > STATE_THRESHOLD) ? ((nib >> 3) & 1u) : 0u;
        cnt += (w.y == 0x13572468u) ? 1u : 0u;
        cnt += (w.z == 0x24681357u) ? 1u : 0u;
    }

#pragma unroll
    for (int off = 32; off > 0; off >>= 1) {
        cnt += __shfl_down(cnt, off);
    }

    if (lane == 0) {
        float potential = membrane[row] + (float)cnt + noise[row];
        out[row] = (potential >= adaptive_thresh[row]) ? 1.0f : 0.0f;
    }
}

extern "C" void kernel_launch(void* const* d_in, const int* in_sizes, int n_in,
                              void* d_out, int out_size, void* d_ws, size_t ws_size,
                              hipStream_t stream) {
    const float* spike_input    = (const float*)d_in[0];
    const float* synapse_states = (const float*)d_in[1];
    const float* membrane       = (const float*)d_in[2];
    const float* adaptive_thr   = (const float*)d_in[3];
    const float* noise          = (const float*)d_in[4];
    float* out = (float*)d_out;

    // Number of 32 KiB chunks available in ws (>= 1 for any sane ws_size).
    unsigned int wsChunks = (unsigned int)(ws_size / (32 * 1024));
    if (wsChunks == 0) wsChunks = 1;

    dim3 grid(OUT_F / 8);   // 1024 blocks, 8 rows per block (1 per wave)
    dim3 block(512);
    snn_gemv_probe_kernel<<<grid, block, 0, stream>>>(
        spike_input, synapse_states, membrane, adaptive_thr, noise,
        (const u32x4*)d_ws, wsChunks, out);
}

// Round 6
// 402.758 us; speedup vs baseline: 1.0551x; 1.0551x over previous
//
#include <hip/hip_runtime.h>
#include <hip/hip_bf16.h>

#define IN_F 8192
#define OUT_F 8192
#define STATE_THRESHOLD 50.0f

typedef float f32x4 __attribute__((ext_vector_type(4)));

// Block-linear streaming: each 512-thread block consumes one contiguous
// 256 KiB tile (8 rows) as a single sliding window — iteration i, thread t
// reads float4 (i*512 + t). The block's combined address order is sequential
// (8 KiB/instruction-step), vs R4's 8 parallel streams 32 KiB apart, to
// maximize DRAM page/channel locality. Row index = i>>2; each thread keeps
// 8 integer row-accumulators and its 16 spike gate bits in registers.
__global__ __launch_bounds__(512, 8) void snn_gemv_kernel(
    const float* __restrict__ spike_input,      // [IN_F]
    const float* __restrict__ synapse_states,   // [OUT_F, IN_F]
    const float* __restrict__ membrane,         // [OUT_F]
    const float* __restrict__ adaptive_thresh,  // [OUT_F]
    const float* __restrict__ noise,            // [OUT_F]
    float* __restrict__ out)                    // [OUT_F]
{
    const int tid  = threadIdx.x;               // 0..511
    const int lane = tid & 63;
    const int wave = tid >> 6;                  // 0..7

    // Prologue: this thread always gates columns 4*(seg*512+tid)+j for
    // seg=0..3 (same within every row). Pack those 16 spike bits into a u32.
    const f32x4* sp4 = (const f32x4*)spike_input;
    unsigned int bits = 0;
#pragma unroll
    for (int seg = 0; seg < 4; ++seg) {
        f32x4 x = sp4[seg * 512 + tid];
        unsigned int nib = (unsigned int)((x.x > 0.5f) | ((x.y > 0.5f) << 1) |
                                          ((x.z > 0.5f) << 2) | ((x.w > 0.5f) << 3));
        bits |= nib << (4 * seg);
    }

    const f32x4* tile =
        (const f32x4*)(synapse_states + (size_t)blockIdx.x * 8 * IN_F);

    unsigned int acc[8] = {0u, 0u, 0u, 0u, 0u, 0u, 0u, 0u};
    // 32 iterations; 4 consecutive iterations = one full row.
#pragma unroll
    for (int i = 0; i < 32; ++i) {
        f32x4 s = __builtin_nontemporal_load(tile + i * 512 + tid);
        unsigned int nib = (bits >> (4 * (i & 3))) & 0xFu;
        unsigned int c = 0;
        c += (s.x > STATE_THRESHOLD) ? (nib & 1u) : 0u;
        c += (s.y > STATE_THRESHOLD) ? ((nib >> 1) & 1u) : 0u;
        c += (s.z > STATE_THRESHOLD) ? ((nib >> 2) & 1u) : 0u;
        c += (s.w > STATE_THRESHOLD) ? ((nib >> 3) & 1u) : 0u;
        acc[i >> 2] += c;
    }

    // Epilogue: 8 wave-reductions (integer, exact), then cross-wave via LDS.
    __shared__ unsigned int part[8][8];         // [wave][row] — 256 B
#pragma unroll
    for (int r = 0; r < 8; ++r) {
        unsigned int v = acc[r];
#pragma unroll
        for (int off = 32; off > 0; off >>= 1) {
            v += __shfl_down(v, off);
        }
        if (lane == 0) part[wave][r] = v;
    }
    __syncthreads();

    if (tid < 8) {
        unsigned int tot = 0;
#pragma unroll
        for (int w = 0; w < 8; ++w) tot += part[w][tid];
        const int row = blockIdx.x * 8 + tid;
        float potential = membrane[row] + (float)tot + noise[row];
        out[row] = (potential >= adaptive_thresh[row]) ? 1.0f : 0.0f;
    }
}

extern "C" void kernel_launch(void* const* d_in, const int* in_sizes, int n_in,
                              void* d_out, int out_size, void* d_ws, size_t ws_size,
                              hipStream_t stream) {
    const float* spike_input    = (const float*)d_in[0];
    const float* synapse_states = (const float*)d_in[1];
    const float* membrane       = (const float*)d_in[2];
    const float* adaptive_thr   = (const float*)d_in[3];
    const float* noise          = (const float*)d_in[4];
    float* out = (float*)d_out;

    dim3 grid(OUT_F / 8);   // 1024 blocks, one 256 KiB tile (8 rows) each
    dim3 block(512);
    snn_gemv_kernel<<<grid, block, 0, stream>>>(
        spike_input, synapse_states, membrane, adaptive_thr, noise, out);
}